// Round 10
// baseline (352.770 us; speedup 1.0000x reference)
//
#include <hip/hip_runtime.h>

// KappaGCN layer on MI355X. KAPPA=-1, N=8192, D=512.
// Round 10: A direct global->VGPR (A fragments have NO intra-block reuse --
// each element lives in one lane and is register-reused across ni; LDS
// staging of A was pure overhead and tied all consumers to the barrier).
// LDS now carries only B (pre-swizzled, global_load_lds, 2 buffers, counted
// vmcnt(10)). A is a 2-tile-deep register pipeline (Pa/Pb, unroll-2, static
// indices) that the compiler waits with precise per-register vmcnt -- no
// barrier interaction. Tile 128x128, 4 waves (2x2, wave 64x64, acc 64 VGPR),
// split-K=4, grid 1024; nt-siblings on one XCD so A is HBM-fetched once.

#define NR 8192
#define DD 512

typedef unsigned int u32;
typedef unsigned short u16;
typedef __attribute__((ext_vector_type(8))) short bf16x8;
typedef __attribute__((ext_vector_type(4))) float f32x4;

__device__ __forceinline__ u16 f2bf(float f) {
  u32 u = __float_as_uint(f);
  u32 r = u + 0x7FFFu + ((u >> 16) & 1u);   // round-to-nearest-even
  return (u16)(r >> 16);
}

__device__ __forceinline__ u32 cvtpk(float lo, float hi) {
  u32 r;
  asm("v_cvt_pk_bf16_f32 %0, %1, %2" : "=v"(r) : "v"(lo), "v"(hi));
  return r;
}

__device__ __forceinline__ void gload16(const void* g, void* l) {
  __builtin_amdgcn_global_load_lds(
      (const __attribute__((address_space(1))) u32*)g,
      (__attribute__((address_space(3))) u32*)l, 16, 0, 0);
}

__device__ __forceinline__ float wred(float v) {
  #pragma unroll
  for (int off = 32; off; off >>= 1) v += __shfl_xor(v, off, 64);
  return v;
}

// W [K=512][N=512] fp32 -> Wt [N][K] bf16, 16B-slot swizzled per 32-k chunk
__global__ __launch_bounds__(256) void conv_wt(const float* __restrict__ W,
                                               u16* __restrict__ Wt) {
  const int idx = blockIdx.x * 256 + threadIdx.x;  // 0..32767
  const int n  = idx >> 6;
  const int k0 = (idx & 63) * 8;
  u32 r[4];
  #pragma unroll
  for (int j = 0; j < 4; ++j) {
    float lo = W[(size_t)(k0 + 2*j    ) * DD + n];
    float hi = W[(size_t)(k0 + 2*j + 1) * DD + n];
    r[j] = (u32)f2bf(lo) | ((u32)f2bf(hi) << 16);
  }
  const int dst = n * DD + ((idx & 63) >> 2) * 32 + (((idx & 3) ^ (n & 3)) * 8);
  *(uint4*)(Wt + dst) = *(const uint4*)r;
}

// ---------------- GEMM: C[M][*] = Af[M][K](fp32, reg-direct) * Bt[*][K] ----
// 128x128 tile, BK=32, 4 waves (2x2), wave tile 64x64 (4x4 frags 16x16x32).
// A: global->VGPR, 2-tile pipeline (Pa/Pb), cvt_pk to bf16 at use.
// B: LDS double-buffer via global_load_lds (pre-swizzled global), counted
// vmcnt(10) per step (8 A-loads + 2 B-stages issued per step).
// DOSUM: nt==0, wn==0 waves add 4 MFMAs vs {g1bf,1} -> denom/alpha partials.
template <int DOSUM>
__global__ __launch_bounds__(256, 2) void gemm_ra(
    const float* __restrict__ Af, const u16* __restrict__ Bt,
    const u16* __restrict__ g1bf,
    float* __restrict__ C0, float* __restrict__ Cext,
    float* __restrict__ denp, float* __restrict__ alp,
    int M, int K, int kchunk, int nkc) {
  __shared__ __align__(16) u16 ldsB[2][4096];   // [128][32] bf16, slot^row&3
  __shared__ __align__(16) u16 ldsG[2048];      // g1bf chunk (DOSUM)

  // decode: b0=mt-low, b1-2=kc, b3-4=nt (A-sharing nt-siblings differ by
  // 8/16/24 -> same XCD L2), b5+=mt-high.
  const int bid = blockIdx.x;
  int mt, nt, kc;
  if (nkc == 4) {
    kc = (bid >> 1) & 3;
    nt = (bid >> 3) & 3;
    mt = ((bid >> 5) << 1) | (bid & 1);
  } else {
    kc = 0;
    nt = bid & 3;
    mt = bid >> 2;
  }

  const int t = threadIdx.x;
  const int lane = t & 63, w = t >> 6;
  const int wm = w >> 1, wn = w & 1;            // 2 x 2 waves
  const int m0 = mt * 128, n0 = nt * 128;
  const int kbeg = kc * kchunk;
  const int lr = lane & 15, lk = lane >> 4;
  const bool doRS = DOSUM && (nt == 0);
  const int nT = kchunk / 32;

  // A: per-lane rolling pointers, 4 frag-rows, 32B each per tile
  const float* aP[4];
  #pragma unroll
  for (int i = 0; i < 4; ++i)
    aP[i] = Af + (size_t)(m0 + wm * 64 + i * 16 + lr) * K + kbeg + lk * 8;

  // B staging (Bt pre-swizzled in global): rows (t>>2)+64j
  const u16* gB = Bt + (size_t)(n0 + (t >> 2)) * K + kbeg + (t & 3) * 8;

  float4 pa0[4], pa1[4], pb0[4], pb1[4];
  auto refill = [&](float4 (&d0)[4], float4 (&d1)[4]) {
    #pragma unroll
    for (int i = 0; i < 4; ++i) {
      d0[i] = *(const float4*)(aP[i]);
      d1[i] = *(const float4*)(aP[i] + 4);
      aP[i] += 32;
    }
  };

  f32x4 acc[4][4];
  #pragma unroll
  for (int i = 0; i < 4; ++i)
    #pragma unroll
    for (int j = 0; j < 4; ++j) acc[i][j] = (f32x4){0.f, 0.f, 0.f, 0.f};
  f32x4 accS[4];
  #pragma unroll
  for (int i = 0; i < 4; ++i) accS[i] = (f32x4){0.f, 0.f, 0.f, 0.f};

  // ---- prologue: ldsG, A(0)->Pa, A(1)->Pb, B(0), B(1); wait B(0) ----
  if (doRS) gload16(g1bf + kbeg + t * 8, &ldsG[t * 8]);
  refill(pa0, pa1);
  refill(pb0, pb1);
  #pragma unroll
  for (int j = 0; j < 2; ++j)
    gload16(gB + (size_t)j * 64 * K, &ldsB[0][t * 8 + j * 2048]);
  #pragma unroll
  for (int j = 0; j < 2; ++j)
    gload16(gB + 32 + (size_t)j * 64 * K, &ldsB[1][t * 8 + j * 2048]);
  asm volatile("s_waitcnt vmcnt(2)" ::: "memory");
  __builtin_amdgcn_s_barrier();
  __builtin_amdgcn_sched_barrier(0);

  auto subiter = [&](int T, float4 (&P0)[4], float4 (&P1)[4], u16* bbuf) {
    // fragment reads from LDS (B) + cvt of A regs (compiler-waited)
    bf16x8 bv[4];
    #pragma unroll
    for (int i = 0; i < 4; ++i)
      bv[i] = *(const bf16x8*)
          &bbuf[(wn * 64 + i * 16 + lr) * 32 + ((lk ^ (lr & 3)) << 3)];
    bf16x8 gvv;
    if (doRS && wn == 0) {
      if (lr == 0) {
        gvv = *(const bf16x8*)&ldsG[T * 32 + lk * 8];
      } else {
        const short s = (lr == 1) ? (short)0x3F80 : (short)0;
        gvv = (bf16x8){s, s, s, s, s, s, s, s};
      }
    }
    bf16x8 af[4];
    #pragma unroll
    for (int i = 0; i < 4; ++i) {
      union { u32 u[4]; bf16x8 v; } pk;
      pk.u[0] = cvtpk(P0[i].x, P0[i].y); pk.u[1] = cvtpk(P0[i].z, P0[i].w);
      pk.u[2] = cvtpk(P1[i].x, P1[i].y); pk.u[3] = cvtpk(P1[i].z, P1[i].w);
      af[i] = pk.v;
    }
    const bool more = (T + 2 < nT);
    if (more) refill(P0, P1);            // A(T+2), 8 loads
    // barrier 1: all waves done reading bbuf before staging overwrites it
    asm volatile("s_waitcnt lgkmcnt(0)" ::: "memory");
    __builtin_amdgcn_sched_barrier(0);
    __builtin_amdgcn_s_barrier();
    __builtin_amdgcn_sched_barrier(0);
    if (more) {                          // B(T+2), 2 gload_lds
      const size_t ko = (size_t)(T + 2) * 32;
      #pragma unroll
      for (int j = 0; j < 2; ++j)
        gload16(gB + ko + (size_t)j * 64 * K, &bbuf[t * 8 + j * 2048]);
    }
    __builtin_amdgcn_sched_barrier(0);
    __builtin_amdgcn_s_setprio(1);
    #pragma unroll
    for (int mi = 0; mi < 4; ++mi)
      #pragma unroll
      for (int ni = 0; ni < 4; ++ni)
        acc[mi][ni] = __builtin_amdgcn_mfma_f32_16x16x32_bf16(
            af[mi], bv[ni], acc[mi][ni], 0, 0, 0);
    if (doRS && wn == 0) {
      #pragma unroll
      for (int i = 0; i < 4; ++i)
        accS[i] = __builtin_amdgcn_mfma_f32_16x16x32_bf16(
            af[i], gvv, accS[i], 0, 0, 0);
    }
    __builtin_amdgcn_s_setprio(0);
    __builtin_amdgcn_sched_barrier(0);
    // barrier 2: B(T+1) complete; A(T+2)+B(T+2) = 10 stay in flight
    if (T + 1 < nT) {
      if (more) asm volatile("s_waitcnt vmcnt(10)" ::: "memory");
      else      asm volatile("s_waitcnt vmcnt(0)"  ::: "memory");
      __builtin_amdgcn_s_barrier();
      __builtin_amdgcn_sched_barrier(0);
    }
  };

  for (int tt = 0; tt < nT; tt += 2) {
    subiter(tt,     pa0, pa1, &ldsB[0][0]);
    subiter(tt + 1, pb0, pb1, &ldsB[1][0]);
  }

  if (doRS && wn == 0 && lr < 2) {
    float* dst = ((lr == 0) ? denp : alp) + (size_t)kc * M + m0 + wm * 64;
    #pragma unroll
    for (int i = 0; i < 4; ++i)
      #pragma unroll
      for (int v = 0; v < 4; ++v)
        dst[i * 16 + lk * 4 + v] = accS[i][v];
  }

  float* C = (kc == 0) ? C0 : (Cext + (size_t)(kc - 1) * M * DD);
  // C/D layout: col = lane&15, row = (lane>>4)*4 + reg   [m89-verified]
  float* Cw = C + (size_t)(m0 + wm * 64 + lk * 4) * DD + n0 + wn * 64 + lr;
  #pragma unroll
  for (int mi = 0; mi < 4; ++mi)
    #pragma unroll
    for (int ni = 0; ni < 4; ++ni)
      #pragma unroll
      for (int v = 0; v < 4; ++v)
        Cw[(size_t)(mi * 16 + v) * DD + ni * 16] = acc[mi][ni][v];
}

// ---------------- row stats (mobius_matvec scalars + gamma) ----------------
__global__ __launch_bounds__(256) void rowstats(const float* __restrict__ X,
                                                const float* __restrict__ mx,
                                                float* __restrict__ fg,
                                                u16* __restrict__ g1bf) {
  const int row  = (blockIdx.x << 2) + (threadIdx.x >> 6);
  const int lane = threadIdx.x & 63;
  const float* xr = X  + (size_t)row * DD + lane * 8;
  const float* mr = mx + (size_t)row * DD + lane * 8;
  float4 a0 = *(const float4*)xr, a1 = *(const float4*)(xr + 4);
  float4 b0 = *(const float4*)mr, b1 = *(const float4*)(mr + 4);
  float sx = a0.x*a0.x + a0.y*a0.y + a0.z*a0.z + a0.w*a0.w
           + a1.x*a1.x + a1.y*a1.y + a1.z*a1.z + a1.w*a1.w;
  float sm = b0.x*b0.x + b0.y*b0.y + b0.z*b0.z + b0.w*b0.w
           + b1.x*b1.x + b1.y*b1.y + b1.z*b1.z + b1.w*b1.w;
  sx = wred(sx); sm = wred(sm);
  if (lane == 0) {
    float xn  = sqrtf(fmaxf(sx, 1e-20f));
    float mxn = sqrtf(fmaxf(sm, 1e-20f));
    float at  = atanhf(fminf(xn, 0.9999999f));
    float t_  = tanhf(mxn / xn * at);
    bool  z   = (mxn <= 1e-10f);
    float factor = z ? 0.f : t_ / mxn;
    float xwsq   = z ? 0.f : t_ * t_ * (sm / (mxn * mxn));
    float g = 2.f / (1.f - xwsq);          // kappa = -1
    g = fmaxf(g, 1e-15f);
    fg[row] = factor * g;
    g1bf[row] = f2bf(g - 1.f);
  }
}

// ---------------- B_T build: Bt[d][j] = fg[j]*mx[j][d], 16B-slot swizzled --
__global__ __launch_bounds__(256) void build_bt(const float* __restrict__ mx,
                                                const float* __restrict__ fg,
                                                u16* __restrict__ Bt) {
  __shared__ float tile[64][65];
  const int j0 = blockIdx.x * 64, d0 = blockIdx.y * 64;
  const int t = threadIdx.x;
  const int r0 = t >> 4, c4 = (t & 15) * 4;
  #pragma unroll
  for (int p = 0; p < 4; ++p) {
    const int r = r0 + p * 16;
    const float s = fg[j0 + r];
    float4 v = *(const float4*)&mx[(size_t)(j0 + r) * DD + d0 + c4];
    tile[r][c4 + 0] = s * v.x; tile[r][c4 + 1] = s * v.y;
    tile[r][c4 + 2] = s * v.z; tile[r][c4 + 3] = s * v.w;
  }
  __syncthreads();
  const int dr = t >> 2, jc = (t & 3) * 16;
  u32 r[8];
  #pragma unroll
  for (int u = 0; u < 8; ++u) {
    float lo = tile[jc + 2 * u][dr];
    float hi = tile[jc + 2 * u + 1][dr];
    r[u] = (u32)f2bf(lo) | ((u32)f2bf(hi) << 16);
  }
  const int s0 = (jc >> 3) & 3;
  const int px = dr & 3;
  u32* rowp = (u32*)(Bt + (size_t)(d0 + dr) * NR + j0 + (jc & 32));
  *(uint4*)(rowp + ((s0 ^ px) * 4))       = *(const uint4*)&r[0];
  *(uint4*)(rowp + (((s0 + 1) ^ px) * 4)) = *(const uint4*)&r[4];
}

// ---------------- epilogue (sums 4 split-K partials + den/al partials) -----
__global__ __launch_bounds__(256) void epilogue(const float* __restrict__ P0,
                                                const float* __restrict__ P1,
                                                const float* __restrict__ P2,
                                                const float* __restrict__ P3,
                                                const float* __restrict__ denp,
                                                const float* __restrict__ alp,
                                                float* __restrict__ out) {
  const int row  = (blockIdx.x << 2) + (threadIdx.x >> 6);
  const int lane = threadIdx.x & 63;
  const size_t ro = (size_t)row * DD + lane * 8;
  float4 n0 = *(const float4*)(P0 + ro), n1 = *(const float4*)(P0 + ro + 4);
  float4 a, b;
  a = *(const float4*)(P1 + ro); b = *(const float4*)(P1 + ro + 4);
  n0.x += a.x; n0.y += a.y; n0.z += a.z; n0.w += a.w;
  n1.x += b.x; n1.y += b.y; n1.z += b.z; n1.w += b.w;
  a = *(const float4*)(P2 + ro); b = *(const float4*)(P2 + ro + 4);
  n0.x += a.x; n0.y += a.y; n0.z += a.z; n0.w += a.w;
  n1.x += b.x; n1.y += b.y; n1.z += b.z; n1.w += b.w;
  a = *(const float4*)(P3 + ro); b = *(const float4*)(P3 + ro + 4);
  n0.x += a.x; n0.y += a.y; n0.z += a.z; n0.w += a.w;
  n1.x += b.x; n1.y += b.y; n1.z += b.z; n1.w += b.w;

  float de = 0.f, alpha = 0.f;
  #pragma unroll
  for (int kc = 0; kc < 4; ++kc) {
    de    += denp[kc * NR + row];
    alpha += alp [kc * NR + row];
  }
  de = (de >= 0.f ? 1.f : -1.f) * fmaxf(fabsf(de), 1e-10f);

  float v[8] = {n0.x / de, n0.y / de, n0.z / de, n0.w / de,
                n1.x / de, n1.y / de, n1.z / de, n1.w / de};
  float sq = 0.f;
  #pragma unroll
  for (int j = 0; j < 8; ++j) sq += v[j] * v[j];
  sq = wred(sq);
  float s1 = 1.f + sqrtf(fmaxf(1.f - sq, 1e-10f));     // 1+sqrt(max(1+k*sq,EPS))
  float an = sqrtf(fmaxf(sq / (s1 * s1), 1e-20f));     // ||a_mean|| clamped
  float t2 = tanhf(alpha * atanhf(fminf(an, 0.9999999f)));
  float f2 = t2 / (an * s1);                           // res = f2 * v
  float xsq = f2 * f2 * sq;
  float xn = sqrtf(fmaxf(xsq, 1e-20f));
  float lf = atanhf(fminf(xn, 0.9999999f)) / xn;       // logmap0 scale
  float u[8]; float us = 0.f;
  #pragma unroll
  for (int j = 0; j < 8; ++j) {
    u[j] = fmaxf(lf * f2 * v[j], 0.f);                 // relu(log0)
    us += u[j] * u[j];
  }
  us = wred(us);
  float un = sqrtf(fmaxf(us, 1e-20f));
  float ef = tanhf(un) / un;                           // expmap0 scale
  float o[8];
  #pragma unroll
  for (int j = 0; j < 8; ++j) o[j] = ef * u[j];
  float* orow = out + (size_t)row * DD + lane * 8;
  *(float4*)orow       = (float4){o[0], o[1], o[2], o[3]};
  *(float4*)(orow + 4) = (float4){o[4], o[5], o[6], o[7]};
}

// ---------------- launch ----------------
extern "C" void kernel_launch(void* const* d_in, const int* in_sizes, int n_in,
                              void* d_out, int out_size, void* d_ws, size_t ws_size,
                              hipStream_t stream) {
  const float* X = (const float*)d_in[0];
  const float* A = (const float*)d_in[1];
  const float* W = (const float*)d_in[2];
  float* out = (float*)d_out;
  char* ws = (char*)d_ws;

  float* mx   = (float*)(ws);                 // 16777216 B (= P0, nom)
  float* Pext = (float*)(ws + 16777216);      // 3 x 16777216 B -> 67108864
  u16*   Bt   = (u16*)(ws + 67108864);        // 8388608 B  -> 75497472
  u16*   Wt   = (u16*)(ws + 75497472);        // 524288 B   -> 76021760
  float* fg   = (float*)(ws + 76021760);      // 32768 B    -> 76054528
  u16*   g1bf = (u16*)(ws + 76054528);        // 16384 B    -> 76070912
  float* denp = (float*)(ws + 76087296);      // 4*32768 B  -> 76218368
  float* alp  = (float*)(ws + 76218368);      // 4*32768 B  -> 76349440

  const size_t MNf = (size_t)NR * DD;         // floats per partial

  conv_wt<<<128, 256, 0, stream>>>(W, Wt);
  // mx = X @ W : M=8192, K=512, grid 64x4, no split
  gemm_ra<0><<<256, 256, 0, stream>>>(X, Wt, g1bf, mx, mx, denp, alp,
                                      NR, DD, DD, 1);
  rowstats<<<2048, 256, 0, stream>>>(X, mx, fg, g1bf);
  build_bt<<<dim3(128, 8), 256, 0, stream>>>(mx, fg, Bt);
  // nom = A @ Bt^T : split-K=4, grid 64x4x4 = 1024
  gemm_ra<1><<<1024, 256, 0, stream>>>(A, Bt, g1bf, mx, Pext, denp, alp,
                                       NR, NR, NR / 4, 4);
  epilogue<<<2048, 256, 0, stream>>>(mx, Pext, Pext + MNf, Pext + 2 * MNf,
                                     denp, alp, out);
}

// Round 12
// 234.641 us; speedup vs baseline: 1.5034x; 1.5034x over previous
//
#include <hip/hip_runtime.h>

// KappaGCN layer on MI355X. KAPPA=-1, N=8192, D=512.
// Round 12: R11 (TLP-first small tile, 4 blk/CU) with the A-staging bug
// fixed. R11 violated the global_load_lds rule: LDS dest is wave-uniform
// base + lane*16B -- R11's A dests had 32B/lane stride, so hardware
// scrambled the A tile (absmax 488). Now A staging is wave-chunked:
// wave w, page j -> chunk c=2w+j covers rows c*8..c*8+7; lane l writes
// LDS floats c*256+l*4 (16B/lane) and fetches logical slot (l&7)^(l>>3)
// of row c*8+(l>>3) (pre-swizzled source; row&7 == l>>3). Reads unchanged.
// Tile 64x128, BK=32, 4 waves (wave 32x64), LDS 36KB -> 4 blocks/CU,
// R2-style __syncthreads loop, split-K=4. denom/alpha fused (wn==0).

#define NR 8192
#define DD 512

typedef unsigned int u32;
typedef unsigned short u16;
typedef __attribute__((ext_vector_type(8))) short bf16x8;
typedef __attribute__((ext_vector_type(4))) float f32x4;

__device__ __forceinline__ u16 f2bf(float f) {
  u32 u = __float_as_uint(f);
  u32 r = u + 0x7FFFu + ((u >> 16) & 1u);   // round-to-nearest-even
  return (u16)(r >> 16);
}

__device__ __forceinline__ u32 cvtpk(float lo, float hi) {
  u32 r;
  asm("v_cvt_pk_bf16_f32 %0, %1, %2" : "=v"(r) : "v"(lo), "v"(hi));
  return r;
}

__device__ __forceinline__ void gload16(const void* g, void* l) {
  __builtin_amdgcn_global_load_lds(
      (const __attribute__((address_space(1))) u32*)g,
      (__attribute__((address_space(3))) u32*)l, 16, 0, 0);
}

__device__ __forceinline__ float wred(float v) {
  #pragma unroll
  for (int off = 32; off; off >>= 1) v += __shfl_xor(v, off, 64);
  return v;
}

// W [K=512][N=512] fp32 -> Wt [N][K] bf16, 16B-slot swizzled per 32-k chunk
__global__ __launch_bounds__(256) void conv_wt(const float* __restrict__ W,
                                               u16* __restrict__ Wt) {
  const int idx = blockIdx.x * 256 + threadIdx.x;  // 0..32767
  const int n  = idx >> 6;
  const int k0 = (idx & 63) * 8;
  u32 r[4];
  #pragma unroll
  for (int j = 0; j < 4; ++j) {
    float lo = W[(size_t)(k0 + 2*j    ) * DD + n];
    float hi = W[(size_t)(k0 + 2*j + 1) * DD + n];
    r[j] = (u32)f2bf(lo) | ((u32)f2bf(hi) << 16);
  }
  const int dst = n * DD + ((idx & 63) >> 2) * 32 + (((idx & 3) ^ (n & 3)) * 8);
  *(uint4*)(Wt + dst) = *(const uint4*)r;
}

// ---------------- GEMM: C[M][*] = Af[M][K](fp32) * Bt[*][K](bf16,swz) ------
// 64x128 tile, BK=32, 4 waves (2x2), wave tile 32x64 (2x4 frags 16x16x32).
// A staged fp32 via global_load_lds (slot^(row&7), pre-swizzled source,
// wave-chunked 16B/lane dests); frags cvt_pk'd to bf16. B pre-swizzled in
// global, staged verbatim. R2-style loop: stage next, read frags, MFMA,
// __syncthreads. DOSUM: nt==0, wn==0 waves add 2 MFMAs vs {g1bf,1}.
template <int DOSUM>
__global__ __launch_bounds__(256, 4) void gemm_s(
    const float* __restrict__ Af, const u16* __restrict__ Bt,
    const u16* __restrict__ g1bf,
    float* __restrict__ C0, float* __restrict__ Cext,
    float* __restrict__ denp, float* __restrict__ alp,
    int M, int K, int kchunk, int nkc) {
  __shared__ __align__(16) float ldsA[2][2048];   // [64][32] f32, slot^row&7
  __shared__ __align__(16) u16   ldsB[2][4096];   // [128][32] bf16, slot^row&3
  __shared__ __align__(16) u16   ldsG[2048];      // g1bf chunk (DOSUM)

  // decode: b0=mt-low, b1-2=kc (XCD pair owns a kc; its B-chunk L2-resident),
  // b3-4=nt (A-sharing nt-siblings differ by 8/16/24 -> same XCD), b5+=mt-hi.
  const int bid = blockIdx.x;
  int mt, nt, kc;
  if (nkc == 4) {
    kc = (bid >> 1) & 3;
    nt = (bid >> 3) & 3;
    mt = ((bid >> 5) << 1) | (bid & 1);
  } else {
    kc = 0;
    nt = bid & 3;
    mt = bid >> 2;
  }

  const int t = threadIdx.x;
  const int lane = t & 63, w = t >> 6;
  const int wm = w >> 1, wn = w & 1;              // 2 x 2 waves
  const int m0 = mt * 64, n0 = nt * 128;
  const int kbeg = kc * kchunk;
  const int lr = lane & 15, lk = lane >> 4, lx = lr & 7;
  const bool doRS = DOSUM && (nt == 0);
  const int nT = kchunk / 32;

  // A staging (wave-chunked): chunk c = 2w+j covers rows c*8..c*8+7.
  // Lane l: row = c*8 + (l>>3); LDS floats c*256 + l*4 (16B/lane, phys slot
  // l&7); source logical slot = (l&7) ^ (l>>3)  [row&7 == l>>3].
  const float* gA[2];
  #pragma unroll
  for (int j = 0; j < 2; ++j) {
    const int row = (2 * w + j) * 8 + (lane >> 3);
    gA[j] = Af + (size_t)(m0 + row) * K + kbeg
          + (((lane & 7) ^ (lane >> 3)) << 2);
  }
  // B staging (verbatim; Bt pre-swizzled): chunk c = 2w+j covers rows
  // c*16..c*16+15 and +64; lane l: row = c*16 + (l>>2), 16B slot l&3.
  const u16* gB = Bt + (size_t)(n0 + (t >> 2)) * K + kbeg + (t & 3) * 8;

  auto stage = [&](int buf, int kt) {
    const int ko = kt * 32;
    #pragma unroll
    for (int j = 0; j < 2; ++j)
      gload16(gA[j] + ko, &ldsA[buf][(2 * w + j) * 256 + lane * 4]);
    gload16(gB + ko,                  &ldsB[buf][t * 8]);
    gload16(gB + ko + (size_t)64 * K, &ldsB[buf][t * 8 + 2048]);
  };

  f32x4 acc[2][4];
  #pragma unroll
  for (int i = 0; i < 2; ++i)
    #pragma unroll
    for (int j = 0; j < 4; ++j) acc[i][j] = (f32x4){0.f, 0.f, 0.f, 0.f};
  f32x4 accS[2];
  accS[0] = (f32x4){0.f, 0.f, 0.f, 0.f};
  accS[1] = (f32x4){0.f, 0.f, 0.f, 0.f};

  // ---- prologue ----
  if (doRS) gload16(g1bf + kbeg + t * 8, &ldsG[t * 8]);
  stage(0, 0);
  __syncthreads();

  for (int tt = 0; tt < nT; ++tt) {
    const int cur = tt & 1;
    if (tt + 1 < nT) stage(cur ^ 1, tt + 1);
    bf16x8 af[2], bv[4];
    #pragma unroll
    for (int i = 0; i < 2; ++i) {
      const int rbase = (wm * 32 + i * 16 + lr) * 32;
      f32x4 lo = *(const f32x4*)&ldsA[cur][rbase + (((2*lk    ) ^ lx) << 2)];
      f32x4 hi = *(const f32x4*)&ldsA[cur][rbase + (((2*lk + 1) ^ lx) << 2)];
      union { u32 u[4]; bf16x8 v; } pk;
      pk.u[0] = cvtpk(lo.x, lo.y); pk.u[1] = cvtpk(lo.z, lo.w);
      pk.u[2] = cvtpk(hi.x, hi.y); pk.u[3] = cvtpk(hi.z, hi.w);
      af[i] = pk.v;
    }
    #pragma unroll
    for (int i = 0; i < 4; ++i) {
      const int rb = (wn * 64 + i * 16 + lr) * 32 + ((lk ^ (lr & 3)) << 3);
      bv[i] = *(const bf16x8*)&ldsB[cur][rb];
    }
    #pragma unroll
    for (int mi = 0; mi < 2; ++mi)
      #pragma unroll
      for (int ni = 0; ni < 4; ++ni)
        acc[mi][ni] = __builtin_amdgcn_mfma_f32_16x16x32_bf16(
            af[mi], bv[ni], acc[mi][ni], 0, 0, 0);
    if (doRS && wn == 0) {
      bf16x8 gv;
      if (lr == 0) {
        gv = *(const bf16x8*)&ldsG[tt * 32 + lk * 8];
      } else {
        const short s = (lr == 1) ? (short)0x3F80 : (short)0;
        gv = (bf16x8){s, s, s, s, s, s, s, s};
      }
      #pragma unroll
      for (int i = 0; i < 2; ++i)
        accS[i] = __builtin_amdgcn_mfma_f32_16x16x32_bf16(
            af[i], gv, accS[i], 0, 0, 0);
    }
    __syncthreads();
  }

  if (doRS && wn == 0 && lr < 2) {
    float* dst = ((lr == 0) ? denp : alp) + (size_t)kc * M + m0 + wm * 32;
    #pragma unroll
    for (int i = 0; i < 2; ++i)
      #pragma unroll
      for (int v = 0; v < 4; ++v)
        dst[i * 16 + lk * 4 + v] = accS[i][v];
  }

  float* C = (kc == 0) ? C0 : (Cext + (size_t)(kc - 1) * M * DD);
  // C/D layout: col = lane&15, row = (lane>>4)*4 + reg   [m89-verified]
  float* Cw = C + (size_t)(m0 + wm * 32 + lk * 4) * DD + n0 + wn * 64 + lr;
  #pragma unroll
  for (int mi = 0; mi < 2; ++mi)
    #pragma unroll
    for (int ni = 0; ni < 4; ++ni)
      #pragma unroll
      for (int v = 0; v < 4; ++v)
        Cw[(size_t)(mi * 16 + v) * DD + ni * 16] = acc[mi][ni][v];
}

// ---------------- row stats (mobius_matvec scalars + gamma) ----------------
__global__ __launch_bounds__(256) void rowstats(const float* __restrict__ X,
                                                const float* __restrict__ mx,
                                                float* __restrict__ fg,
                                                u16* __restrict__ g1bf) {
  const int row  = (blockIdx.x << 2) + (threadIdx.x >> 6);
  const int lane = threadIdx.x & 63;
  const float* xr = X  + (size_t)row * DD + lane * 8;
  const float* mr = mx + (size_t)row * DD + lane * 8;
  float4 a0 = *(const float4*)xr, a1 = *(const float4*)(xr + 4);
  float4 b0 = *(const float4*)mr, b1 = *(const float4*)(mr + 4);
  float sx = a0.x*a0.x + a0.y*a0.y + a0.z*a0.z + a0.w*a0.w
           + a1.x*a1.x + a1.y*a1.y + a1.z*a1.z + a1.w*a1.w;
  float sm = b0.x*b0.x + b0.y*b0.y + b0.z*b0.z + b0.w*b0.w
           + b1.x*b1.x + b1.y*b1.y + b1.z*b1.z + b1.w*b1.w;
  sx = wred(sx); sm = wred(sm);
  if (lane == 0) {
    float xn  = sqrtf(fmaxf(sx, 1e-20f));
    float mxn = sqrtf(fmaxf(sm, 1e-20f));
    float at  = atanhf(fminf(xn, 0.9999999f));
    float t_  = tanhf(mxn / xn * at);
    bool  z   = (mxn <= 1e-10f);
    float factor = z ? 0.f : t_ / mxn;
    float xwsq   = z ? 0.f : t_ * t_ * (sm / (mxn * mxn));
    float g = 2.f / (1.f - xwsq);          // kappa = -1
    g = fmaxf(g, 1e-15f);
    fg[row] = factor * g;
    g1bf[row] = f2bf(g - 1.f);
  }
}

// ---------------- B_T build: Bt[d][j] = fg[j]*mx[j][d], 16B-slot swizzled --
__global__ __launch_bounds__(256) void build_bt(const float* __restrict__ mx,
                                                const float* __restrict__ fg,
                                                u16* __restrict__ Bt) {
  __shared__ float tile[64][65];
  const int j0 = blockIdx.x * 64, d0 = blockIdx.y * 64;
  const int t = threadIdx.x;
  const int r0 = t >> 4, c4 = (t & 15) * 4;
  #pragma unroll
  for (int p = 0; p < 4; ++p) {
    const int r = r0 + p * 16;
    const float s = fg[j0 + r];
    float4 v = *(const float4*)&mx[(size_t)(j0 + r) * DD + d0 + c4];
    tile[r][c4 + 0] = s * v.x; tile[r][c4 + 1] = s * v.y;
    tile[r][c4 + 2] = s * v.z; tile[r][c4 + 3] = s * v.w;
  }
  __syncthreads();
  const int dr = t >> 2, jc = (t & 3) * 16;
  u32 r[8];
  #pragma unroll
  for (int u = 0; u < 8; ++u) {
    float lo = tile[jc + 2 * u][dr];
    float hi = tile[jc + 2 * u + 1][dr];
    r[u] = (u32)f2bf(lo) | ((u32)f2bf(hi) << 16);
  }
  const int s0 = (jc >> 3) & 3;
  const int px = dr & 3;
  u32* rowp = (u32*)(Bt + (size_t)(d0 + dr) * NR + j0 + (jc & 32));
  *(uint4*)(rowp + ((s0 ^ px) * 4))       = *(const uint4*)&r[0];
  *(uint4*)(rowp + (((s0 + 1) ^ px) * 4)) = *(const uint4*)&r[4];
}

// ---------------- epilogue (sums 4 split-K partials + den/al partials) -----
__global__ __launch_bounds__(256) void epilogue(const float* __restrict__ P0,
                                                const float* __restrict__ P1,
                                                const float* __restrict__ P2,
                                                const float* __restrict__ P3,
                                                const float* __restrict__ denp,
                                                const float* __restrict__ alp,
                                                float* __restrict__ out) {
  const int row  = (blockIdx.x << 2) + (threadIdx.x >> 6);
  const int lane = threadIdx.x & 63;
  const size_t ro = (size_t)row * DD + lane * 8;
  float4 n0 = *(const float4*)(P0 + ro), n1 = *(const float4*)(P0 + ro + 4);
  float4 a, b;
  a = *(const float4*)(P1 + ro); b = *(const float4*)(P1 + ro + 4);
  n0.x += a.x; n0.y += a.y; n0.z += a.z; n0.w += a.w;
  n1.x += b.x; n1.y += b.y; n1.z += b.z; n1.w += b.w;
  a = *(const float4*)(P2 + ro); b = *(const float4*)(P2 + ro + 4);
  n0.x += a.x; n0.y += a.y; n0.z += a.z; n0.w += a.w;
  n1.x += b.x; n1.y += b.y; n1.z += b.z; n1.w += b.w;
  a = *(const float4*)(P3 + ro); b = *(const float4*)(P3 + ro + 4);
  n0.x += a.x; n0.y += a.y; n0.z += a.z; n0.w += a.w;
  n1.x += b.x; n1.y += b.y; n1.z += b.z; n1.w += b.w;

  float de = 0.f, alpha = 0.f;
  #pragma unroll
  for (int kc = 0; kc < 4; ++kc) {
    de    += denp[kc * NR + row];
    alpha += alp [kc * NR + row];
  }
  de = (de >= 0.f ? 1.f : -1.f) * fmaxf(fabsf(de), 1e-10f);

  float v[8] = {n0.x / de, n0.y / de, n0.z / de, n0.w / de,
                n1.x / de, n1.y / de, n1.z / de, n1.w / de};
  float sq = 0.f;
  #pragma unroll
  for (int j = 0; j < 8; ++j) sq += v[j] * v[j];
  sq = wred(sq);
  float s1 = 1.f + sqrtf(fmaxf(1.f - sq, 1e-10f));     // 1+sqrt(max(1+k*sq,EPS))
  float an = sqrtf(fmaxf(sq / (s1 * s1), 1e-20f));     // ||a_mean|| clamped
  float t2 = tanhf(alpha * atanhf(fminf(an, 0.9999999f)));
  float f2 = t2 / (an * s1);                           // res = f2 * v
  float xsq = f2 * f2 * sq;
  float xn = sqrtf(fmaxf(xsq, 1e-20f));
  float lf = atanhf(fminf(xn, 0.9999999f)) / xn;       // logmap0 scale
  float u[8]; float us = 0.f;
  #pragma unroll
  for (int j = 0; j < 8; ++j) {
    u[j] = fmaxf(lf * f2 * v[j], 0.f);                 // relu(log0)
    us += u[j] * u[j];
  }
  us = wred(us);
  float un = sqrtf(fmaxf(us, 1e-20f));
  float ef = tanhf(un) / un;                           // expmap0 scale
  float o[8];
  #pragma unroll
  for (int j = 0; j < 8; ++j) o[j] = ef * u[j];
  float* orow = out + (size_t)row * DD + lane * 8;
  *(float4*)orow       = (float4){o[0], o[1], o[2], o[3]};
  *(float4*)(orow + 4) = (float4){o[4], o[5], o[6], o[7]};
}

// ---------------- launch ----------------
extern "C" void kernel_launch(void* const* d_in, const int* in_sizes, int n_in,
                              void* d_out, int out_size, void* d_ws, size_t ws_size,
                              hipStream_t stream) {
  const float* X = (const float*)d_in[0];
  const float* A = (const float*)d_in[1];
  const float* W = (const float*)d_in[2];
  float* out = (float*)d_out;
  char* ws = (char*)d_ws;

  float* mx   = (float*)(ws);                 // 16777216 B (= P0, nom)
  float* Pext = (float*)(ws + 16777216);      // 3 x 16777216 B -> 67108864
  u16*   Bt   = (u16*)(ws + 67108864);        // 8388608 B  -> 75497472
  u16*   Wt   = (u16*)(ws + 75497472);        // 524288 B   -> 76021760
  float* fg   = (float*)(ws + 76021760);      // 32768 B    -> 76054528
  u16*   g1bf = (u16*)(ws + 76054528);        // 16384 B    -> 76070912
  float* denp = (float*)(ws + 76087296);      // 4*32768 B  -> 76218368
  float* alp  = (float*)(ws + 76218368);      // 4*32768 B  -> 76349440

  const size_t MNf = (size_t)NR * DD;         // floats per partial

  conv_wt<<<128, 256, 0, stream>>>(W, Wt);
  // mx = X @ W : M=8192, K=512 -> grid 128mt x 4nt = 512, no split
  gemm_s<0><<<512, 256, 0, stream>>>(X, Wt, g1bf, mx, mx, denp, alp,
                                     NR, DD, DD, 1);
  rowstats<<<2048, 256, 0, stream>>>(X, mx, fg, g1bf);
  build_bt<<<dim3(128, 8), 256, 0, stream>>>(mx, fg, Bt);
  // nom = A @ Bt^T : split-K=4 -> grid 128mt x 4nt x 4kc = 2048 (8/CU queued)
  gemm_s<1><<<2048, 256, 0, stream>>>(A, Bt, g1bf, mx, Pext, denp, alp,
                                      NR, NR, NR / 4, 4);
  epilogue<<<2048, 256, 0, stream>>>(mx, Pext, Pext + MNf, Pext + 2 * MNf,
                                     denp, alp, out);
}

// Round 13
// 220.669 us; speedup vs baseline: 1.5986x; 1.0633x over previous
//
#include <hip/hip_runtime.h>

// KappaGCN layer on MI355X. KAPPA=-1, N=8192, D=512.
// Round 13: 8-phase-template port for the fused fp32-A GEMM. Evidence R7-R12:
// every 2-phase variant is stuck at 380-550 TF at ANY occupancy (m233: the
// stage+vmcnt+barrier drain is ~72% of the 2-phase critical path). The
// template (T3+T4) splits each K-step into phases {ds_read chunk || stage
// issue -> barrier -> prio MFMA cluster -> barrier} with counted vmcnt only
// once per K-step. BM=256 BN=256 BK=32, 8 waves (2x4, wave 128x64), THREE
// LDS buffers (stage t+2 never collides with readers of t): A 32K*3 + B
// 16K*3 + G 4K = 148KB, 1 blk/CU. denom/alpha stay fused (wn==0 waves).
// mx GEMM keeps the R9 gemm_ph structure (small, ~10us).

#define NR 8192
#define DD 512

typedef unsigned int u32;
typedef unsigned short u16;
typedef __attribute__((ext_vector_type(8))) short bf16x8;
typedef __attribute__((ext_vector_type(4))) float f32x4;

__device__ __forceinline__ u16 f2bf(float f) {
  u32 u = __float_as_uint(f);
  u32 r = u + 0x7FFFu + ((u >> 16) & 1u);   // round-to-nearest-even
  return (u16)(r >> 16);
}

__device__ __forceinline__ u32 cvtpk(float lo, float hi) {
  u32 r;
  asm("v_cvt_pk_bf16_f32 %0, %1, %2" : "=v"(r) : "v"(lo), "v"(hi));
  return r;
}

__device__ __forceinline__ void gload16(const void* g, void* l) {
  __builtin_amdgcn_global_load_lds(
      (const __attribute__((address_space(1))) u32*)g,
      (__attribute__((address_space(3))) u32*)l, 16, 0, 0);
}

__device__ __forceinline__ float wred(float v) {
  #pragma unroll
  for (int off = 32; off; off >>= 1) v += __shfl_xor(v, off, 64);
  return v;
}

// W [K=512][N=512] fp32 -> Wt [N][K] bf16, 16B-slot swizzled per 32-k chunk
__global__ __launch_bounds__(256) void conv_wt(const float* __restrict__ W,
                                               u16* __restrict__ Wt) {
  const int idx = blockIdx.x * 256 + threadIdx.x;  // 0..32767
  const int n  = idx >> 6;
  const int k0 = (idx & 63) * 8;
  u32 r[4];
  #pragma unroll
  for (int j = 0; j < 4; ++j) {
    float lo = W[(size_t)(k0 + 2*j    ) * DD + n];
    float hi = W[(size_t)(k0 + 2*j + 1) * DD + n];
    r[j] = (u32)f2bf(lo) | ((u32)f2bf(hi) << 16);
  }
  const int dst = n * DD + ((idx & 63) >> 2) * 32 + (((idx & 3) ^ (n & 3)) * 8);
  *(uint4*)(Wt + dst) = *(const uint4*)r;
}

// ---------------- 8-phase GEMM: C[M][512] = Af[M][K](fp32) * Bt[*][K] ------
// 256x256 tile, BK=32, 8 waves (2x4), wave tile 128x64 (8x4 frags 16x16x32).
// 3 LDS buffers; per K-step 4 phases; vmcnt(6) once per step (phase 3).
// DOSUM: nt==0, wn==0 waves add 2 MFMAs/phase vs {g1bf,1}.
template <int DOSUM>
__global__ __launch_bounds__(512, 2) void gemm8(
    const float* __restrict__ Af, const u16* __restrict__ Bt,
    const u16* __restrict__ g1bf,
    float* __restrict__ C0, float* __restrict__ Cext,
    float* __restrict__ denp, float* __restrict__ alp,
    int M, int K, int kchunk, int nkc) {
  __shared__ __align__(16) float ldsA[3][8192];   // [256][32] f32, slot^row&7
  __shared__ __align__(16) u16   ldsB[3][8192];   // [256][32] bf16, slot^row&3
  __shared__ __align__(16) u16   ldsG[2048];      // g1bf chunk (DOSUM)

  // decode: b0-1=kc (each kc owned by XCD pair {kc,kc+4}), b2=mt-low,
  // b3=nt (A-sharing nt-siblings differ by 8 -> same XCD), b4+=mt-high.
  const int bid = blockIdx.x;
  int mt, nt, kc;
  if (nkc == 4) {
    kc = bid & 3;
    nt = (bid >> 3) & 1;
    mt = ((bid >> 4) << 1) | ((bid >> 2) & 1);
  } else {
    kc = 0;
    nt = bid & 1;
    mt = bid >> 1;
  }

  const int t = threadIdx.x;
  const int lane = t & 63, w = t >> 6;
  const int wm = w >> 2, wn = w & 3;              // 2 x 4 waves
  const int m0 = mt * 256, n0 = nt * 256;
  const int kbeg = kc * kchunk;
  const int lr = lane & 15, lk = lane >> 4, lx = lr & 7;
  const bool doRS = DOSUM && (nt == 0);
  const int nT = kchunk / 32;

  // A staging: thread t -> rows (t>>3)+64j, phys slot t&7, 16B/lane dests;
  // source fetches logical slot (t&7)^(row&7) (pre-swizzle; row&7=(t>>3)&7).
  const int rowA = t >> 3;
  const int scol = ((t & 7) ^ (rowA & 7)) << 2;   // floats
  const float* gA0 = Af + (size_t)(m0 + rowA) * K + kbeg + scol;
  // B staging (verbatim; Bt pre-swizzled in global): rows (t>>2)+128j
  const u16* gB = Bt + (size_t)(n0 + (t >> 2)) * K + kbeg + (t & 3) * 8;

  f32x4 acc[8][4];
  #pragma unroll
  for (int i = 0; i < 8; ++i)
    #pragma unroll
    for (int j = 0; j < 4; ++j) acc[i][j] = (f32x4){0.f, 0.f, 0.f, 0.f};
  f32x4 accS[8];
  #pragma unroll
  for (int i = 0; i < 8; ++i) accS[i] = (f32x4){0.f, 0.f, 0.f, 0.f};

  auto stageA2 = [&](int buf, int kt, int j0) {   // 2 of 4 A-chunks
    const int ko = kt * 32;
    gload16(gA0 + ko + (size_t)(j0    ) * 64 * K, &ldsA[buf][t * 4 + (j0    ) * 2048]);
    gload16(gA0 + ko + (size_t)(j0 + 1) * 64 * K, &ldsA[buf][t * 4 + (j0 + 1) * 2048]);
  };
  auto stageB2 = [&](int buf, int kt) {           // both B-chunks
    const int ko = kt * 32;
    gload16(gB + ko,                    &ldsB[buf][t * 8]);
    gload16(gB + ko + (size_t)128 * K,  &ldsB[buf][t * 8 + 4096]);
  };

  // ---- prologue: ldsG + tiles 0,1 (6 loads each); wait ldsG+tile0 ----
  if (doRS && t < 256) gload16(g1bf + kbeg + t * 8, &ldsG[t * 8]);
  stageA2(0, 0, 0); stageA2(0, 0, 2); stageB2(0, 0);
  stageA2(1, 1, 0); stageA2(1, 1, 2); stageB2(1, 1);
  asm volatile("s_waitcnt vmcnt(6)" ::: "memory");
  __builtin_amdgcn_s_barrier();
  __builtin_amdgcn_sched_barrier(0);

  for (int tt = 0; tt < nT; ++tt) {
    const int b  = tt % 3;
    const int sb = (tt + 2) % 3;
    const bool pf = (tt + 2 < nT);
    // B frags for the whole K-step (read once, used by all 4 phases)
    bf16x8 bv[4];
    #pragma unroll
    for (int i = 0; i < 4; ++i)
      bv[i] = *(const bf16x8*)
          &ldsB[b][(wn * 64 + i * 16 + lr) * 32 + ((lk ^ (lr & 3)) << 3)];
    bf16x8 gv;
    if (doRS && wn == 0) {
      if (lr == 0) {
        gv = *(const bf16x8*)&ldsG[tt * 32 + lk * 8];
      } else {
        const short s = (lr == 1) ? (short)0x3F80 : (short)0;
        gv = (bf16x8){s, s, s, s, s, s, s, s};
      }
    }
    #pragma unroll
    for (int p = 0; p < 4; ++p) {
      // ---- phase p: read A frags 2p,2p+1; issue stage chunk; mfma ----
      bf16x8 afa, afb;
      {
        const int ra = (wm * 128 + (2 * p) * 16 + lr) * 32;
        f32x4 lo = *(const f32x4*)&ldsA[b][ra + (((2 * lk    ) ^ lx) << 2)];
        f32x4 hi = *(const f32x4*)&ldsA[b][ra + (((2 * lk + 1) ^ lx) << 2)];
        union { u32 u[4]; bf16x8 v; } pk;
        pk.u[0] = cvtpk(lo.x, lo.y); pk.u[1] = cvtpk(lo.z, lo.w);
        pk.u[2] = cvtpk(hi.x, hi.y); pk.u[3] = cvtpk(hi.z, hi.w);
        afa = pk.v;
      }
      {
        const int ra = (wm * 128 + (2 * p + 1) * 16 + lr) * 32;
        f32x4 lo = *(const f32x4*)&ldsA[b][ra + (((2 * lk    ) ^ lx) << 2)];
        f32x4 hi = *(const f32x4*)&ldsA[b][ra + (((2 * lk + 1) ^ lx) << 2)];
        union { u32 u[4]; bf16x8 v; } pk;
        pk.u[0] = cvtpk(lo.x, lo.y); pk.u[1] = cvtpk(lo.z, lo.w);
        pk.u[2] = cvtpk(hi.x, hi.y); pk.u[3] = cvtpk(hi.z, hi.w);
        afb = pk.v;
      }
      if (p == 0 && pf) stageA2(sb, tt + 2, 0);
      if (p == 1 && pf) stageA2(sb, tt + 2, 2);
      if (p == 2 && pf) stageB2(sb, tt + 2);
      __builtin_amdgcn_s_barrier();
      __builtin_amdgcn_sched_barrier(0);
      __builtin_amdgcn_s_setprio(1);
      #pragma unroll
      for (int ni = 0; ni < 4; ++ni) {
        acc[2 * p    ][ni] = __builtin_amdgcn_mfma_f32_16x16x32_bf16(
            afa, bv[ni], acc[2 * p    ][ni], 0, 0, 0);
        acc[2 * p + 1][ni] = __builtin_amdgcn_mfma_f32_16x16x32_bf16(
            afb, bv[ni], acc[2 * p + 1][ni], 0, 0, 0);
      }
      if (doRS && wn == 0) {
        accS[2 * p    ] = __builtin_amdgcn_mfma_f32_16x16x32_bf16(
            afa, gv, accS[2 * p    ], 0, 0, 0);
        accS[2 * p + 1] = __builtin_amdgcn_mfma_f32_16x16x32_bf16(
            afb, gv, accS[2 * p + 1], 0, 0, 0);
      }
      __builtin_amdgcn_s_setprio(0);
      __builtin_amdgcn_sched_barrier(0);
      if (p == 3 && tt + 1 < nT) {
        if (pf) asm volatile("s_waitcnt vmcnt(6)" ::: "memory");
        else    asm volatile("s_waitcnt vmcnt(0)" ::: "memory");
      }
      __builtin_amdgcn_s_barrier();
      __builtin_amdgcn_sched_barrier(0);
    }
  }

  if (doRS && wn == 0 && lr < 2) {
    float* dst = ((lr == 0) ? denp : alp) + (size_t)kc * M + m0 + wm * 128;
    #pragma unroll
    for (int i = 0; i < 8; ++i)
      #pragma unroll
      for (int v = 0; v < 4; ++v)
        dst[i * 16 + lk * 4 + v] = accS[i][v];
  }

  float* C = (kc == 0) ? C0 : (Cext + (size_t)(kc - 1) * M * DD);
  // C/D layout: col = lane&15, row = (lane>>4)*4 + reg   [m89-verified]
  float* Cw = C + (size_t)(m0 + wm * 128 + lk * 4) * DD + n0 + wn * 64 + lr;
  #pragma unroll
  for (int mi = 0; mi < 8; ++mi)
    #pragma unroll
    for (int ni = 0; ni < 4; ++ni)
      #pragma unroll
      for (int v = 0; v < 4; ++v)
        Cw[(size_t)(mi * 16 + v) * DD + ni * 16] = acc[mi][ni][v];
}

// ---------------- R9-style 2-phase GEMM (used for mx = X@W only) -----------
__global__ __launch_bounds__(256, 2) void gemm_ph(
    const float* __restrict__ Af, const u16* __restrict__ Bt,
    float* __restrict__ C0, int M, int K) {
  __shared__ __align__(16) float ldsA[2][4096];   // [128][32] f32, slot^row&7
  __shared__ __align__(16) u16   ldsB[2][8192];   // [256][32] bf16, slot^row&3
  const int bid = blockIdx.x;
  const int nt = bid & 1;
  const int mt = bid >> 1;

  const int t = threadIdx.x;
  const int lane = t & 63, w = t >> 6;
  const int wm = w >> 1, wn = w & 1;
  const int m0 = mt * 128, n0 = nt * 256;
  const int lr = lane & 15, lk = lane >> 4, lx = lr & 7;

  const int scol = ((t & 7) ^ ((t >> 3) & 7)) << 2;
  const float* gA0 = Af + (size_t)(m0 + (t >> 3)) * K + scol;
  const u16* gB = Bt + (size_t)(n0 + (t >> 2)) * K + (t & 3) * 8;

  auto stage = [&](int buf, int kt) {
    const int ko = kt * 32;
    #pragma unroll
    for (int j = 0; j < 4; ++j)
      gload16(gA0 + ko + (size_t)j * 32 * K, &ldsA[buf][t * 4 + j * 1024]);
    #pragma unroll
    for (int j = 0; j < 4; ++j)
      gload16(gB + ko + (size_t)j * 64 * K, &ldsB[buf][t * 8 + j * 2048]);
  };

  f32x4 acc[4][8];
  #pragma unroll
  for (int i = 0; i < 4; ++i)
    #pragma unroll
    for (int j = 0; j < 8; ++j) acc[i][j] = (f32x4){0.f, 0.f, 0.f, 0.f};

  const int nT = K / 32;
  stage(0, 0);
  __syncthreads();
  for (int tt = 0; tt < nT; ++tt) {
    const int cur = tt & 1;
    if (tt + 1 < nT) stage(cur ^ 1, tt + 1);
    bf16x8 af[4], bv[8];
    #pragma unroll
    for (int i = 0; i < 4; ++i) {
      const int rbase = (wm * 64 + i * 16 + lr) * 32;
      f32x4 lo = *(const f32x4*)&ldsA[cur][rbase + (((2*lk    ) ^ lx) << 2)];
      f32x4 hi = *(const f32x4*)&ldsA[cur][rbase + (((2*lk + 1) ^ lx) << 2)];
      union { u32 u[4]; bf16x8 v; } pk;
      pk.u[0] = cvtpk(lo.x, lo.y); pk.u[1] = cvtpk(lo.z, lo.w);
      pk.u[2] = cvtpk(hi.x, hi.y); pk.u[3] = cvtpk(hi.z, hi.w);
      af[i] = pk.v;
    }
    #pragma unroll
    for (int i = 0; i < 8; ++i) {
      const int rb = (wn * 128 + i * 16 + lr) * 32 + ((lk ^ (lr & 3)) << 3);
      bv[i] = *(const bf16x8*)&ldsB[cur][rb];
    }
    #pragma unroll
    for (int mi = 0; mi < 4; ++mi)
      #pragma unroll
      for (int ni = 0; ni < 8; ++ni)
        acc[mi][ni] = __builtin_amdgcn_mfma_f32_16x16x32_bf16(
            af[mi], bv[ni], acc[mi][ni], 0, 0, 0);
    __syncthreads();
  }

  float* Cw = C0 + (size_t)(m0 + wm * 64 + lk * 4) * DD + n0 + wn * 128 + lr;
  #pragma unroll
  for (int mi = 0; mi < 4; ++mi)
    #pragma unroll
    for (int ni = 0; ni < 8; ++ni)
      #pragma unroll
      for (int v = 0; v < 4; ++v)
        Cw[(size_t)(mi * 16 + v) * DD + ni * 16] = acc[mi][ni][v];
}

// ---------------- row stats (mobius_matvec scalars + gamma) ----------------
__global__ __launch_bounds__(256) void rowstats(const float* __restrict__ X,
                                                const float* __restrict__ mx,
                                                float* __restrict__ fg,
                                                u16* __restrict__ g1bf) {
  const int row  = (blockIdx.x << 2) + (threadIdx.x >> 6);
  const int lane = threadIdx.x & 63;
  const float* xr = X  + (size_t)row * DD + lane * 8;
  const float* mr = mx + (size_t)row * DD + lane * 8;
  float4 a0 = *(const float4*)xr, a1 = *(const float4*)(xr + 4);
  float4 b0 = *(const float4*)mr, b1 = *(const float4*)(mr + 4);
  float sx = a0.x*a0.x + a0.y*a0.y + a0.z*a0.z + a0.w*a0.w
           + a1.x*a1.x + a1.y*a1.y + a1.z*a1.z + a1.w*a1.w;
  float sm = b0.x*b0.x + b0.y*b0.y + b0.z*b0.z + b0.w*b0.w
           + b1.x*b1.x + b1.y*b1.y + b1.z*b1.z + b1.w*b1.w;
  sx = wred(sx); sm = wred(sm);
  if (lane == 0) {
    float xn  = sqrtf(fmaxf(sx, 1e-20f));
    float mxn = sqrtf(fmaxf(sm, 1e-20f));
    float at  = atanhf(fminf(xn, 0.9999999f));
    float t_  = tanhf(mxn / xn * at);
    bool  z   = (mxn <= 1e-10f);
    float factor = z ? 0.f : t_ / mxn;
    float xwsq   = z ? 0.f : t_ * t_ * (sm / (mxn * mxn));
    float g = 2.f / (1.f - xwsq);          // kappa = -1
    g = fmaxf(g, 1e-15f);
    fg[row] = factor * g;
    g1bf[row] = f2bf(g - 1.f);
  }
}

// ---------------- B_T build: Bt[d][j] = fg[j]*mx[j][d], 16B-slot swizzled --
__global__ __launch_bounds__(256) void build_bt(const float* __restrict__ mx,
                                                const float* __restrict__ fg,
                                                u16* __restrict__ Bt) {
  __shared__ float tile[64][65];
  const int j0 = blockIdx.x * 64, d0 = blockIdx.y * 64;
  const int t = threadIdx.x;
  const int r0 = t >> 4, c4 = (t & 15) * 4;
  #pragma unroll
  for (int p = 0; p < 4; ++p) {
    const int r = r0 + p * 16;
    const float s = fg[j0 + r];
    float4 v = *(const float4*)&mx[(size_t)(j0 + r) * DD + d0 + c4];
    tile[r][c4 + 0] = s * v.x; tile[r][c4 + 1] = s * v.y;
    tile[r][c4 + 2] = s * v.z; tile[r][c4 + 3] = s * v.w;
  }
  __syncthreads();
  const int dr = t >> 2, jc = (t & 3) * 16;
  u32 r[8];
  #pragma unroll
  for (int u = 0; u < 8; ++u) {
    float lo = tile[jc + 2 * u][dr];
    float hi = tile[jc + 2 * u + 1][dr];
    r[u] = (u32)f2bf(lo) | ((u32)f2bf(hi) << 16);
  }
  const int s0 = (jc >> 3) & 3;
  const int px = dr & 3;
  u32* rowp = (u32*)(Bt + (size_t)(d0 + dr) * NR + j0 + (jc & 32));
  *(uint4*)(rowp + ((s0 ^ px) * 4))       = *(const uint4*)&r[0];
  *(uint4*)(rowp + (((s0 + 1) ^ px) * 4)) = *(const uint4*)&r[4];
}

// ---------------- epilogue (sums 4 split-K partials + den/al partials) -----
__global__ __launch_bounds__(256) void epilogue(const float* __restrict__ P0,
                                                const float* __restrict__ P1,
                                                const float* __restrict__ P2,
                                                const float* __restrict__ P3,
                                                const float* __restrict__ denp,
                                                const float* __restrict__ alp,
                                                float* __restrict__ out) {
  const int row  = (blockIdx.x << 2) + (threadIdx.x >> 6);
  const int lane = threadIdx.x & 63;
  const size_t ro = (size_t)row * DD + lane * 8;
  float4 n0 = *(const float4*)(P0 + ro), n1 = *(const float4*)(P0 + ro + 4);
  float4 a, b;
  a = *(const float4*)(P1 + ro); b = *(const float4*)(P1 + ro + 4);
  n0.x += a.x; n0.y += a.y; n0.z += a.z; n0.w += a.w;
  n1.x += b.x; n1.y += b.y; n1.z += b.z; n1.w += b.w;
  a = *(const float4*)(P2 + ro); b = *(const float4*)(P2 + ro + 4);
  n0.x += a.x; n0.y += a.y; n0.z += a.z; n0.w += a.w;
  n1.x += b.x; n1.y += b.y; n1.z += b.z; n1.w += b.w;
  a = *(const float4*)(P3 + ro); b = *(const float4*)(P3 + ro + 4);
  n0.x += a.x; n0.y += a.y; n0.z += a.z; n0.w += a.w;
  n1.x += b.x; n1.y += b.y; n1.z += b.z; n1.w += b.w;

  float de = 0.f, alpha = 0.f;
  #pragma unroll
  for (int kc = 0; kc < 4; ++kc) {
    de    += denp[kc * NR + row];
    alpha += alp [kc * NR + row];
  }
  de = (de >= 0.f ? 1.f : -1.f) * fmaxf(fabsf(de), 1e-10f);

  float v[8] = {n0.x / de, n0.y / de, n0.z / de, n0.w / de,
                n1.x / de, n1.y / de, n1.z / de, n1.w / de};
  float sq = 0.f;
  #pragma unroll
  for (int j = 0; j < 8; ++j) sq += v[j] * v[j];
  sq = wred(sq);
  float s1 = 1.f + sqrtf(fmaxf(1.f - sq, 1e-10f));     // 1+sqrt(max(1+k*sq,EPS))
  float an = sqrtf(fmaxf(sq / (s1 * s1), 1e-20f));     // ||a_mean|| clamped
  float t2 = tanhf(alpha * atanhf(fminf(an, 0.9999999f)));
  float f2 = t2 / (an * s1);                           // res = f2 * v
  float xsq = f2 * f2 * sq;
  float xn = sqrtf(fmaxf(xsq, 1e-20f));
  float lf = atanhf(fminf(xn, 0.9999999f)) / xn;       // logmap0 scale
  float u[8]; float us = 0.f;
  #pragma unroll
  for (int j = 0; j < 8; ++j) {
    u[j] = fmaxf(lf * f2 * v[j], 0.f);                 // relu(log0)
    us += u[j] * u[j];
  }
  us = wred(us);
  float un = sqrtf(fmaxf(us, 1e-20f));
  float ef = tanhf(un) / un;                           // expmap0 scale
  float o[8];
  #pragma unroll
  for (int j = 0; j < 8; ++j) o[j] = ef * u[j];
  float* orow = out + (size_t)row * DD + lane * 8;
  *(float4*)orow       = (float4){o[0], o[1], o[2], o[3]};
  *(float4*)(orow + 4) = (float4){o[4], o[5], o[6], o[7]};
}

// ---------------- launch ----------------
extern "C" void kernel_launch(void* const* d_in, const int* in_sizes, int n_in,
                              void* d_out, int out_size, void* d_ws, size_t ws_size,
                              hipStream_t stream) {
  const float* X = (const float*)d_in[0];
  const float* A = (const float*)d_in[1];
  const float* W = (const float*)d_in[2];
  float* out = (float*)d_out;
  char* ws = (char*)d_ws;

  float* mx   = (float*)(ws);                 // 16777216 B (= P0, nom)
  float* Pext = (float*)(ws + 16777216);      // 3 x 16777216 B -> 67108864
  u16*   Bt   = (u16*)(ws + 67108864);        // 8388608 B  -> 75497472
  u16*   Wt   = (u16*)(ws + 75497472);        // 524288 B   -> 76021760
  float* fg   = (float*)(ws + 76021760);      // 32768 B    -> 76054528
  u16*   g1bf = (u16*)(ws + 76054528);        // 16384 B    -> 76070912
  float* denp = (float*)(ws + 76087296);      // 4*32768 B  -> 76218368
  float* alp  = (float*)(ws + 76218368);      // 4*32768 B  -> 76349440

  const size_t MNf = (size_t)NR * DD;         // floats per partial

  conv_wt<<<128, 256, 0, stream>>>(W, Wt);
  // mx = X @ W : 128x256 tile -> grid 64mt x 2nt = 128
  gemm_ph<<<128, 256, 0, stream>>>(X, Wt, mx, NR, DD);
  rowstats<<<2048, 256, 0, stream>>>(X, mx, fg, g1bf);
  build_bt<<<dim3(128, 8), 256, 0, stream>>>(mx, fg, Bt);
  // nom = A @ Bt^T : 8-phase 256x256, split-K=4 -> grid 32x2x4 = 256
  gemm8<1><<<256, 512, 0, stream>>>(A, Bt, g1bf, mx, Pext, denp, alp,
                                    NR, NR, NR / 4, 4);
  epilogue<<<2048, 256, 0, stream>>>(mx, Pext, Pext + MNf, Pext + 2 * MNf,
                                     denp, alp, out);
}